// Round 7
// baseline (562.357 us; speedup 1.0000x reference)
//
#include <hip/hip_runtime.h>
#include <hip/hip_fp16.h>
#include <math.h>

#define LEAKY 0.2f
#define BP 6                     // nodes per bucket = 64
#define BSZ 64
#define NBUK_MAX 2048

typedef _Float16 f16x8 __attribute__((ext_vector_type(8)));
typedef float f32x4 __attribute__((ext_vector_type(4)));

union H2 { __half2 h; int i; };
union H8 { __half2 h[4]; float4 f; };

__device__ inline __half2 shfl_xor_h2(__half2 v, int m) {
    H2 u; u.h = v;
    u.i = __shfl_xor(u.i, m);
    return u.h;
}

// ---------------- CSR build (block-local binning) ----------------

__global__ __launch_bounds__(256) void khist(const int* __restrict__ dst,
                                             int* __restrict__ bhist,
                                             int E, int nbuk) {
    __shared__ int hist[NBUK_MAX];
    int t = threadIdx.x;
    for (int i = t; i < nbuk; i += 256) hist[i] = 0;
    __syncthreads();
    for (int e = blockIdx.x * 256 + t; e < E; e += gridDim.x * 256)
        atomicAdd(&hist[dst[e] >> BP], 1);
    __syncthreads();
    for (int i = t; i < nbuk; i += 256) {
        int v = hist[i];
        if (v) atomicAdd(&bhist[i], v);
    }
}

__global__ __launch_bounds__(1024) void bscan(const int* __restrict__ bhist,
                                              int* __restrict__ bbase,
                                              int* __restrict__ bcur, int nbuk) {
    __shared__ int s[1024];
    int t = threadIdx.x;
    int v[4]; int sum = 0;
    #pragma unroll
    for (int i = 0; i < 4; ++i) {
        int idx = t * 4 + i;
        v[i] = (idx < nbuk) ? bhist[idx] : 0;
        sum += v[i];
    }
    s[t] = sum; __syncthreads();
    for (int off = 1; off < 1024; off <<= 1) {
        int a = (t >= off) ? s[t - off] : 0;
        __syncthreads();
        s[t] += a;
        __syncthreads();
    }
    int run = (t > 0) ? s[t - 1] : 0;
    #pragma unroll
    for (int i = 0; i < 4; ++i) {
        int idx = t * 4 + i;
        if (idx < nbuk) { bbase[idx] = run; bcur[idx] = run; run += v[i]; }
    }
    if (t == 1023) bbase[nbuk] = s[1023];
}

__global__ __launch_bounds__(256) void kscatter2(const int* __restrict__ src,
                                                 const int* __restrict__ dst,
                                                 int* __restrict__ bcur,
                                                 int* __restrict__ ebuf,
                                                 int E, int nbuk, int chunk) {
    __shared__ int hist[NBUK_MAX];
    int t = threadIdx.x;
    int base = blockIdx.x * chunk;
    int end = min(base + chunk, E);
    for (int i = t; i < nbuk; i += 256) hist[i] = 0;
    __syncthreads();
    for (int e = base + t; e < end; e += 256)
        atomicAdd(&hist[dst[e] >> BP], 1);
    __syncthreads();
    for (int i = t; i < nbuk; i += 256) {
        int c = hist[i];
        hist[i] = c ? atomicAdd(&bcur[i], c) : 0;
    }
    __syncthreads();
    for (int e = base + t; e < end; e += 256) {
        int d = dst[e];
        int pos = atomicAdd(&hist[d >> BP], 1);
        ebuf[pos] = ((d & (BSZ - 1)) << 17) | src[e];
    }
}

__global__ __launch_bounds__(256) void kcount(const int* __restrict__ ebuf,
                                              const int* __restrict__ bbase,
                                              int* __restrict__ cnt,
                                              float* __restrict__ dis, int N) {
    __shared__ int h[BSZ];
    int b = blockIdx.x, t = threadIdx.x;
    if (t < BSZ) h[t] = 0;
    __syncthreads();
    int beg = bbase[b], end = bbase[b + 1];
    for (int j = beg + t; j < end; j += 256)
        atomicAdd(&h[(ebuf[j] >> 17) & (BSZ - 1)], 1);
    __syncthreads();
    if (t < BSZ) {
        int node = b * BSZ + t;
        if (node < N) {
            int c = h[t] + 1;
            cnt[node] = c;
            dis[node] = rsqrtf((float)c);
        }
    }
}

__global__ void scan_block(const int* __restrict__ cnt, int* rowptr, int* bsum, int n) {
    __shared__ int s[256];
    int t = threadIdx.x;
    int i = blockIdx.x * 256 + t;
    int v = (i < n) ? cnt[i] : 0;
    s[t] = v; __syncthreads();
    for (int off = 1; off < 256; off <<= 1) {
        int a = (t >= off) ? s[t - off] : 0;
        __syncthreads();
        s[t] += a;
        __syncthreads();
    }
    if (i < n) rowptr[i] = s[t] - v;
    if (t == 255) bsum[blockIdx.x] = s[255];
}

__global__ void scan_tops(int* bsum, int nb, int* rowptr, int n) {
    __shared__ int s[512];
    int t = threadIdx.x;
    int v = (t < nb) ? bsum[t] : 0;
    s[t] = v; __syncthreads();
    for (int off = 1; off < 512; off <<= 1) {
        int a = (t >= off) ? s[t - off] : 0;
        __syncthreads();
        s[t] += a;
        __syncthreads();
    }
    if (t < nb) bsum[t] = s[t] - v;
    if (t == 511) rowptr[n] = s[511];
}

__global__ void scan_add(int* rowptr, const int* __restrict__ bsum, int n) {
    int i = blockIdx.x * 256 + threadIdx.x;
    if (i < n) rowptr[i] += bsum[blockIdx.x];
}

__global__ __launch_bounds__(256) void kplace(const int* __restrict__ ebuf,
                                              const int* __restrict__ bbase,
                                              const int* __restrict__ rowptr,
                                              int* __restrict__ col, int N) {
    __shared__ int cur[BSZ];
    int b = blockIdx.x, t = threadIdx.x;
    if (t < BSZ) {
        int node = b * BSZ + t;
        if (node < N) {
            int r = rowptr[node];
            col[r] = node;          // self-loop
            cur[t] = r + 1;
        }
    }
    __syncthreads();
    int beg = bbase[b], end = bbase[b + 1];
    for (int j = beg + t; j < end; j += 256) {
        int v = ebuf[j];
        int dl = (v >> 17) & (BSZ - 1);
        int p = atomicAdd(&cur[dl], 1);
        col[p] = v & 0x1FFFF;
    }
}

// ---------------- weight transposes (fp32 -> fp16, [k][n] -> [n][k]) ----------------
__global__ __launch_bounds__(256) void wtrans(const float* __restrict__ W1,
                                              const float* __restrict__ W2,
                                              __half* __restrict__ W1t,
                                              __half* __restrict__ W2t) {
    int idx = blockIdx.x * 256 + threadIdx.x;
    if (idx < 32768) {
        int n = idx >> 8, k = idx & 255;              // W1t[128][256]
        W1t[idx] = __float2half(W1[k * 128 + n]);
    } else if (idx < 32768 + 2048) {
        int i = idx - 32768;
        int n = i >> 7, k = i & 127;                  // W2t[16][128]
        W2t[i] = __float2half(W2[k * 16 + n]);
    }
}

// ---------------- GEMM1: [M,256]fp32 @ W1t[128,256]fp16 -> fp16, *= dis[row] ----------------
// MFMA 16x16x32_f16, no LDS. Wave handles 16 rows x 128 cols.
__global__ __launch_bounds__(256) void gemm1_mfma(
        const float* __restrict__ x, const __half* __restrict__ W1t,
        const float* __restrict__ dis, __half* __restrict__ C, int M) {
    int wave = threadIdx.x >> 6;
    int lane = threadIdx.x & 63;
    int m = lane & 15, q = lane >> 4;
    int row0 = (blockIdx.x * 4 + wave) * 16;
    int arow = row0 + m;
    bool aval = arow < M;
    const float* xr = x + (size_t)arow * 256 + q * 8;
    f32x4 acc[8];
    #pragma unroll
    for (int c = 0; c < 8; ++c) acc[c] = (f32x4){0.f, 0.f, 0.f, 0.f};
    for (int k0 = 0; k0 < 256; k0 += 32) {
        f16x8 a;
        if (aval) {
            float4 v0 = *(const float4*)(xr + k0);
            float4 v1 = *(const float4*)(xr + k0 + 4);
            a[0] = (_Float16)v0.x; a[1] = (_Float16)v0.y;
            a[2] = (_Float16)v0.z; a[3] = (_Float16)v0.w;
            a[4] = (_Float16)v1.x; a[5] = (_Float16)v1.y;
            a[6] = (_Float16)v1.z; a[7] = (_Float16)v1.w;
        } else {
            #pragma unroll
            for (int i = 0; i < 8; ++i) a[i] = (_Float16)0.f;
        }
        #pragma unroll
        for (int c = 0; c < 8; ++c) {
            f16x8 b = *(const f16x8*)(W1t + (size_t)(c * 16 + m) * 256 + k0 + q * 8);
            acc[c] = __builtin_amdgcn_mfma_f32_16x16x32_f16(a, b, acc[c], 0, 0, 0);
        }
    }
    float dw[4];
    #pragma unroll
    for (int r = 0; r < 4; ++r) {
        int rr = row0 + q * 4 + r;
        dw[r] = (rr < M) ? dis[rr] : 0.f;
    }
    #pragma unroll
    for (int c = 0; c < 8; ++c) {
        #pragma unroll
        for (int r = 0; r < 4; ++r) {
            int rr = row0 + q * 4 + r;
            if (rr < M)
                C[(size_t)rr * 128 + c * 16 + m] = __float2half(acc[c][r] * dw[r]);
        }
    }
}

// ---------------- GEMM2: x1h[M,128]fp16 @ W2t[16,128]fp16 -> fp16, *= dis[row] ----------------
__global__ __launch_bounds__(256) void gemm2_mfma(
        const __half* __restrict__ A, const __half* __restrict__ W2t,
        const float* __restrict__ dis, __half* __restrict__ C, int M) {
    int wave = threadIdx.x >> 6;
    int lane = threadIdx.x & 63;
    int m = lane & 15, q = lane >> 4;
    int row0 = (blockIdx.x * 4 + wave) * 16;
    int arow = row0 + m;
    bool aval = arow < M;
    const __half* ar = A + (size_t)arow * 128 + q * 8;
    f32x4 acc = (f32x4){0.f, 0.f, 0.f, 0.f};
    #pragma unroll
    for (int k0 = 0; k0 < 128; k0 += 32) {
        f16x8 a;
        if (aval) {
            a = *(const f16x8*)(ar + k0);
        } else {
            #pragma unroll
            for (int i = 0; i < 8; ++i) a[i] = (_Float16)0.f;
        }
        f16x8 b = *(const f16x8*)(W2t + (size_t)m * 128 + k0 + q * 8);
        acc = __builtin_amdgcn_mfma_f32_16x16x32_f16(a, b, acc, 0, 0, 0);
    }
    #pragma unroll
    for (int r = 0; r < 4; ++r) {
        int rr = row0 + q * 4 + r;
        if (rr < M)
            C[(size_t)rr * 16 + m] = __float2half(acc[r] * dis[rr]);
    }
}

// ---------------- prop128: wave/node, 4 edge slots x 16 lanes x float4, unroll 4 ----------------
__global__ __launch_bounds__(256) void prop128(
        const __half* __restrict__ h, const int* __restrict__ rowptr,
        const int* __restrict__ col, const float* __restrict__ dis,
        const float* __restrict__ bias, __half* __restrict__ out, int N) {
    int n = (blockIdx.x * 256 + threadIdx.x) >> 6;
    if (n >= N) return;
    int lane = threadIdx.x & 63;
    int eo = lane >> 4;
    int q = lane & 15;
    const float4* __restrict__ h4 = (const float4*)h;
    int beg = rowptr[n], end = rowptr[n + 1];
    __half2 acc[4];
    acc[0] = acc[1] = acc[2] = acc[3] = __float2half2_rn(0.f);
    int j = beg + eo;
    for (; j + 12 < end; j += 16) {     // 16 edges in flight per wave
        int s0 = col[j], s1 = col[j + 4], s2 = col[j + 8], s3 = col[j + 12];
        H8 u0, u1, u2, u3;
        u0.f = h4[(size_t)s0 * 16 + q];
        u1.f = h4[(size_t)s1 * 16 + q];
        u2.f = h4[(size_t)s2 * 16 + q];
        u3.f = h4[(size_t)s3 * 16 + q];
        #pragma unroll
        for (int i = 0; i < 4; ++i) acc[i] = __hadd2(acc[i], u0.h[i]);
        #pragma unroll
        for (int i = 0; i < 4; ++i) acc[i] = __hadd2(acc[i], u1.h[i]);
        #pragma unroll
        for (int i = 0; i < 4; ++i) acc[i] = __hadd2(acc[i], u2.h[i]);
        #pragma unroll
        for (int i = 0; i < 4; ++i) acc[i] = __hadd2(acc[i], u3.h[i]);
    }
    for (; j + 4 < end; j += 8) {
        int s0 = col[j], s1 = col[j + 4];
        H8 u0, u1;
        u0.f = h4[(size_t)s0 * 16 + q];
        u1.f = h4[(size_t)s1 * 16 + q];
        #pragma unroll
        for (int i = 0; i < 4; ++i) acc[i] = __hadd2(acc[i], u0.h[i]);
        #pragma unroll
        for (int i = 0; i < 4; ++i) acc[i] = __hadd2(acc[i], u1.h[i]);
    }
    for (; j < end; j += 4) {
        int s = col[j];
        H8 u; u.f = h4[(size_t)s * 16 + q];
        #pragma unroll
        for (int i = 0; i < 4; ++i) acc[i] = __hadd2(acc[i], u.h[i]);
    }
    #pragma unroll
    for (int i = 0; i < 4; ++i) {
        acc[i] = __hadd2(acc[i], shfl_xor_h2(acc[i], 16));
        acc[i] = __hadd2(acc[i], shfl_xor_h2(acc[i], 32));
    }
    if (eo == 0) {
        float dn = dis[n];
        const float4* b4 = (const float4*)bias;
        float4 bA = b4[q * 2];
        float4 bB = b4[q * 2 + 1];
        float2 f0 = __half22float2(acc[0]);
        float2 f1 = __half22float2(acc[1]);
        float2 f2 = __half22float2(acc[2]);
        float2 f3 = __half22float2(acc[3]);
        float o0 = fmaf(dn, f0.x, bA.x), o1 = fmaf(dn, f0.y, bA.y);
        float o2 = fmaf(dn, f1.x, bA.z), o3 = fmaf(dn, f1.y, bA.w);
        float o4 = fmaf(dn, f2.x, bB.x), o5 = fmaf(dn, f2.y, bB.y);
        float o6 = fmaf(dn, f3.x, bB.z), o7 = fmaf(dn, f3.y, bB.w);
        o0 = o0 > 0.f ? o0 : LEAKY * o0;  o1 = o1 > 0.f ? o1 : LEAKY * o1;
        o2 = o2 > 0.f ? o2 : LEAKY * o2;  o3 = o3 > 0.f ? o3 : LEAKY * o3;
        o4 = o4 > 0.f ? o4 : LEAKY * o4;  o5 = o5 > 0.f ? o5 : LEAKY * o5;
        o6 = o6 > 0.f ? o6 : LEAKY * o6;  o7 = o7 > 0.f ? o7 : LEAKY * o7;
        H8 w;
        w.h[0] = __floats2half2_rn(o0, o1);
        w.h[1] = __floats2half2_rn(o2, o3);
        w.h[2] = __floats2half2_rn(o4, o5);
        w.h[3] = __floats2half2_rn(o6, o7);
        ((float4*)out)[(size_t)n * 16 + q] = w.f;
    }
}

// ---------------- prop16 ----------------
__global__ __launch_bounds__(256) void prop16(
        const __half* __restrict__ h, const int* __restrict__ rowptr,
        const int* __restrict__ col, const float* __restrict__ dis,
        const float* __restrict__ bias, void* __restrict__ outp,
        int N, int act, int post, int out_fp16) {
    int t = blockIdx.x * 256 + threadIdx.x;
    int n = t >> 4;
    if (n >= N) return;
    int li = threadIdx.x & 15;
    int eo = li >> 3;
    int hq = li & 7;
    const int* __restrict__ h2i = (const int*)h;
    int beg = rowptr[n], end = rowptr[n + 1];
    __half2 acc = __float2half2_rn(0.f);
    int j = beg + eo;
    for (; j + 6 < end; j += 8) {
        H2 u0, u1, u2, u3;
        u0.i = h2i[(size_t)col[j]     * 8 + hq];
        u1.i = h2i[(size_t)col[j + 2] * 8 + hq];
        u2.i = h2i[(size_t)col[j + 4] * 8 + hq];
        u3.i = h2i[(size_t)col[j + 6] * 8 + hq];
        acc = __hadd2(acc, u0.h);
        acc = __hadd2(acc, u1.h);
        acc = __hadd2(acc, u2.h);
        acc = __hadd2(acc, u3.h);
    }
    for (; j < end; j += 2) {
        H2 u; u.i = h2i[(size_t)col[j] * 8 + hq];
        acc = __hadd2(acc, u.h);
    }
    acc = __hadd2(acc, shfl_xor_h2(acc, 8));
    if (eo == 0) {
        float dn = dis[n];
        float2 f = __half22float2(acc);
        float ox = dn * f.x, oy = dn * f.y;
        if (act) {
            ox += bias[hq * 2];
            oy += bias[hq * 2 + 1];
            ox = ox > 0.f ? ox : LEAKY * ox;
            oy = oy > 0.f ? oy : LEAKY * oy;
        }
        if (post) { ox *= dn; oy *= dn; }
        if (out_fp16) {
            H2 w; w.h = __floats2half2_rn(ox, oy);
            ((int*)outp)[(size_t)n * 8 + hq] = w.i;
        } else {
            ((float2*)outp)[(size_t)n * 8 + hq] = make_float2(ox, oy);
        }
    }
}

// ---------------- GEMM3: [M,16] @ [16,40] + b ----------------
__global__ __launch_bounds__(256) void gemm_16_40(
        const float* __restrict__ P, const float* __restrict__ W,
        const float* __restrict__ b, float* __restrict__ out, int total) {
    __shared__ float sw[16 * 40];
    __shared__ float sb[40];
    int t = threadIdx.x;
    for (int i = t; i < 640; i += 256) sw[i] = W[i];
    if (t < 40) sb[t] = b[t];
    __syncthreads();
    int idx = blockIdx.x * 256 + t;
    if (idx >= total) return;
    int n = idx / 40, c = idx % 40;
    float acc = sb[c];
    const float* pr = P + (size_t)n * 16;
    #pragma unroll
    for (int k = 0; k < 16; ++k) acc += pr[k] * sw[k * 40 + c];
    out[idx] = acc;
}

// ---------------- launch ----------------

extern "C" void kernel_launch(void* const* d_in, const int* in_sizes, int n_in,
                              void* d_out, int out_size, void* d_ws, size_t ws_size,
                              hipStream_t stream) {
    const float* x  = (const float*)d_in[0];
    const int*   ei = (const int*)d_in[1];
    const float* W1 = (const float*)d_in[2];
    const float* b1 = (const float*)d_in[3];
    const float* W2 = (const float*)d_in[4];
    const float* b2 = (const float*)d_in[5];
    const float* W3 = (const float*)d_in[6];
    const float* b3 = (const float*)d_in[7];
    float* out = (float*)d_out;

    int N = in_sizes[0] / 256;   // 100000
    int E = in_sizes[1] / 2;     // 3200000
    const int* src = ei;
    const int* dst = ei + E;
    int NBUK = (N + BSZ - 1) >> BP;   // 1563

    char* w = (char*)d_ws;
    auto alloc = [&](size_t bytes) {
        char* p = w;
        w += (bytes + 255) & ~(size_t)255;
        return p;
    };
    int NB = (N + 255) / 256;
    int*    cnt     = (int*)   alloc((size_t)N * 4);
    int*    rowptr  = (int*)   alloc((size_t)(N + 1) * 4);
    int*    bsum    = (int*)   alloc((size_t)NB * 4);
    int*    bhist   = (int*)   alloc((size_t)NBUK * 4);
    int*    bbase   = (int*)   alloc((size_t)(NBUK + 1) * 4);
    int*    bcur    = (int*)   alloc((size_t)NBUK * 4);
    int*    ebuf    = (int*)   alloc((size_t)E * 4);
    int*    colx    = (int*)   alloc((size_t)(E + N) * 4);
    float*  dis     = (float*) alloc((size_t)N * 4);
    __half* W1t     = (__half*)alloc((size_t)128 * 256 * 2);
    __half* W2t     = (__half*)alloc((size_t)16 * 128 * 2);
    __half* h1h     = (__half*)alloc((size_t)N * 128 * 2);
    __half* x1h     = (__half*)alloc((size_t)N * 128 * 2);
    __half* h2h     = (__half*)alloc((size_t)N * 16 * 2);
    __half* x2h     = (__half*)alloc((size_t)N * 16 * 2);
    float*  p3      = (float*) alloc((size_t)N * 16 * 4);

    (void)hipMemsetAsync(bhist, 0, (size_t)NBUK * 4, stream);
    wtrans  <<<136, 256, 0, stream>>>(W1, W2, W1t, W2t);
    khist   <<<256, 256, 0, stream>>>(dst, bhist, E, NBUK);
    bscan   <<<1, 1024, 0, stream>>>(bhist, bbase, bcur, NBUK);
    int SC_BLOCKS = 256;
    int chunk = (E + SC_BLOCKS - 1) / SC_BLOCKS;
    kscatter2<<<SC_BLOCKS, 256, 0, stream>>>(src, dst, bcur, ebuf, E, NBUK, chunk);
    kcount  <<<NBUK, 256, 0, stream>>>(ebuf, bbase, cnt, dis, N);
    scan_block<<<NB, 256, 0, stream>>>(cnt, rowptr, bsum, N);
    scan_tops <<<1, 512, 0, stream>>>(bsum, NB, rowptr, N);
    scan_add  <<<NB, 256, 0, stream>>>(rowptr, bsum, N);
    kplace  <<<NBUK, 256, 0, stream>>>(ebuf, bbase, rowptr, colx, N);

    int gtiles = (N + 63) / 64;
    gemm1_mfma<<<gtiles, 256, 0, stream>>>(x, W1t, dis, h1h, N);
    prop128   <<<(N * 64 + 255) / 256, 256, 0, stream>>>(h1h, rowptr, colx,
                                                         dis, b1, x1h, N);
    gemm2_mfma<<<gtiles, 256, 0, stream>>>(x1h, W2t, dis, h2h, N);
    prop16    <<<(N * 16 + 255) / 256, 256, 0, stream>>>(h2h, rowptr, colx,
                                                         dis, b2, x2h, N, 1, 1, 1);
    prop16    <<<(N * 16 + 255) / 256, 256, 0, stream>>>(x2h, rowptr, colx,
                                                         dis, nullptr, p3, N, 0, 0, 0);
    gemm_16_40<<<(N * 40 + 255) / 256, 256, 0, stream>>>(p3, W3, b3, out,
                                                         N * 40);
}

// Round 8
// 535.107 us; speedup vs baseline: 1.0509x; 1.0509x over previous
//
#include <hip/hip_runtime.h>
#include <hip/hip_fp16.h>
#include <math.h>

#define LEAKY 0.2f
#define BP 6                     // nodes per bucket = 64
#define BSZ 64
#define NBUK_MAX 2048

typedef _Float16 f16x8 __attribute__((ext_vector_type(8)));
typedef float f32x4 __attribute__((ext_vector_type(4)));

union H2 { __half2 h; int i; };
union H8 { __half2 h[4]; float4 f; };

__device__ inline __half2 shfl_xor_h2(__half2 v, int m) {
    H2 u; u.h = v;
    u.i = __shfl_xor(u.i, m);
    return u.h;
}

// ---------------- kinit: khist (blocks 0..255) + weight transpose (256..391) ----------------
__global__ __launch_bounds__(256) void kinit(const int* __restrict__ dst,
                                             int* __restrict__ bhist,
                                             int E, int nbuk,
                                             const float* __restrict__ W1,
                                             const float* __restrict__ W2,
                                             __half* __restrict__ W1t,
                                             __half* __restrict__ W2t) {
    if (blockIdx.x < 256) {
        __shared__ int hist[NBUK_MAX];
        int t = threadIdx.x;
        for (int i = t; i < nbuk; i += 256) hist[i] = 0;
        __syncthreads();
        for (int e = blockIdx.x * 256 + t; e < E; e += 65536)
            atomicAdd(&hist[dst[e] >> BP], 1);
        __syncthreads();
        for (int i = t; i < nbuk; i += 256) {
            int v = hist[i];
            if (v) atomicAdd(&bhist[i], v);
        }
    } else {
        int idx = (blockIdx.x - 256) * 256 + threadIdx.x;
        if (idx < 32768) {
            int n = idx >> 8, k = idx & 255;              // W1t[128][256]
            W1t[idx] = __float2half(W1[k * 128 + n]);
        } else if (idx < 32768 + 2048) {
            int i = idx - 32768;
            int n = i >> 7, k = i & 127;                  // W2t[16][128]
            W2t[i] = __float2half(W2[k * 16 + n]);
        }
    }
}

// single-block exclusive scan of bucket counts -> bbase, bcur
__global__ __launch_bounds__(1024) void bscan(const int* __restrict__ bhist,
                                              int* __restrict__ bbase,
                                              int* __restrict__ bcur, int nbuk) {
    __shared__ int s[1024];
    int t = threadIdx.x;
    int v[4]; int sum = 0;
    #pragma unroll
    for (int i = 0; i < 4; ++i) {
        int idx = t * 4 + i;
        v[i] = (idx < nbuk) ? bhist[idx] : 0;
        sum += v[i];
    }
    s[t] = sum; __syncthreads();
    for (int off = 1; off < 1024; off <<= 1) {
        int a = (t >= off) ? s[t - off] : 0;
        __syncthreads();
        s[t] += a;
        __syncthreads();
    }
    int run = (t > 0) ? s[t - 1] : 0;
    #pragma unroll
    for (int i = 0; i < 4; ++i) {
        int idx = t * 4 + i;
        if (idx < nbuk) { bbase[idx] = run; bcur[idx] = run; run += v[i]; }
    }
    if (t == 1023) bbase[nbuk] = s[1023];
}

// block-local binning scatter
__global__ __launch_bounds__(256) void kscatter2(const int* __restrict__ src,
                                                 const int* __restrict__ dst,
                                                 int* __restrict__ bcur,
                                                 int* __restrict__ ebuf,
                                                 int E, int nbuk, int chunk) {
    __shared__ int hist[NBUK_MAX];
    int t = threadIdx.x;
    int base = blockIdx.x * chunk;
    int end = min(base + chunk, E);
    for (int i = t; i < nbuk; i += 256) hist[i] = 0;
    __syncthreads();
    for (int e = base + t; e < end; e += 256)
        atomicAdd(&hist[dst[e] >> BP], 1);
    __syncthreads();
    for (int i = t; i < nbuk; i += 256) {
        int c = hist[i];
        hist[i] = c ? atomicAdd(&bcur[i], c) : 0;
    }
    __syncthreads();
    for (int e = base + t; e < end; e += 256) {
        int d = dst[e];
        int pos = atomicAdd(&hist[d >> BP], 1);
        ebuf[pos] = ((d & (BSZ - 1)) << 17) | src[e];
    }
}

// per-bucket counts -> rowptr (direct, via wave scan) + dis. No global scan needed:
// col region of bucket b starts at bbase[b] + b*64 (64 self-loops per full bucket).
__global__ __launch_bounds__(256) void kcount_scan(const int* __restrict__ ebuf,
                                                   const int* __restrict__ bbase,
                                                   int* __restrict__ rowptr,
                                                   float* __restrict__ dis, int N) {
    __shared__ int h[BSZ];
    int b = blockIdx.x, t = threadIdx.x;
    if (t < BSZ) h[t] = 0;
    __syncthreads();
    int beg = bbase[b], end = bbase[b + 1];
    for (int j = beg + t; j < end; j += 256)
        atomicAdd(&h[(ebuf[j] >> 17) & (BSZ - 1)], 1);
    __syncthreads();
    if (t < BSZ) {                      // threads 0..63 = wave 0
        int node = b * BSZ + t;
        int c = (node < N) ? h[t] + 1 : 0;   // +1 self-loop
        int incl = c;
        #pragma unroll
        for (int off = 1; off < 64; off <<= 1) {
            int v = __shfl_up(incl, off);
            if (t >= off) incl += v;
        }
        int colbase = beg + b * BSZ;
        if (node < N) {
            rowptr[node] = colbase + incl - c;
            dis[node] = rsqrtf((float)c);
            if (node == N - 1) rowptr[N] = colbase + incl;
        }
    }
}

// per-bucket placement into col (self-loop first, then bucket edges)
__global__ __launch_bounds__(256) void kplace(const int* __restrict__ ebuf,
                                              const int* __restrict__ bbase,
                                              const int* __restrict__ rowptr,
                                              int* __restrict__ col, int N) {
    __shared__ int cur[BSZ];
    int b = blockIdx.x, t = threadIdx.x;
    if (t < BSZ) {
        int node = b * BSZ + t;
        if (node < N) {
            int r = rowptr[node];
            col[r] = node;          // self-loop
            cur[t] = r + 1;
        }
    }
    __syncthreads();
    int beg = bbase[b], end = bbase[b + 1];
    for (int j = beg + t; j < end; j += 256) {
        int v = ebuf[j];
        int dl = (v >> 17) & (BSZ - 1);
        int p = atomicAdd(&cur[dl], 1);
        col[p] = v & 0x1FFFF;
    }
}

// ---------------- GEMM1: [M,256]fp32 @ W1t[128,256]fp16 -> fp16, *= dis[row] ----------------
__global__ __launch_bounds__(256) void gemm1_mfma(
        const float* __restrict__ x, const __half* __restrict__ W1t,
        const float* __restrict__ dis, __half* __restrict__ C, int M) {
    int wave = threadIdx.x >> 6;
    int lane = threadIdx.x & 63;
    int m = lane & 15, q = lane >> 4;
    int row0 = (blockIdx.x * 4 + wave) * 16;
    int arow = row0 + m;
    bool aval = arow < M;
    const float* xr = x + (size_t)arow * 256 + q * 8;
    f32x4 acc[8];
    #pragma unroll
    for (int c = 0; c < 8; ++c) acc[c] = (f32x4){0.f, 0.f, 0.f, 0.f};
    for (int k0 = 0; k0 < 256; k0 += 32) {
        f16x8 a;
        if (aval) {
            float4 v0 = *(const float4*)(xr + k0);
            float4 v1 = *(const float4*)(xr + k0 + 4);
            a[0] = (_Float16)v0.x; a[1] = (_Float16)v0.y;
            a[2] = (_Float16)v0.z; a[3] = (_Float16)v0.w;
            a[4] = (_Float16)v1.x; a[5] = (_Float16)v1.y;
            a[6] = (_Float16)v1.z; a[7] = (_Float16)v1.w;
        } else {
            #pragma unroll
            for (int i = 0; i < 8; ++i) a[i] = (_Float16)0.f;
        }
        #pragma unroll
        for (int c = 0; c < 8; ++c) {
            f16x8 b = *(const f16x8*)(W1t + (size_t)(c * 16 + m) * 256 + k0 + q * 8);
            acc[c] = __builtin_amdgcn_mfma_f32_16x16x32_f16(a, b, acc[c], 0, 0, 0);
        }
    }
    float dw[4];
    #pragma unroll
    for (int r = 0; r < 4; ++r) {
        int rr = row0 + q * 4 + r;
        dw[r] = (rr < M) ? dis[rr] : 0.f;
    }
    #pragma unroll
    for (int c = 0; c < 8; ++c) {
        #pragma unroll
        for (int r = 0; r < 4; ++r) {
            int rr = row0 + q * 4 + r;
            if (rr < M)
                C[(size_t)rr * 128 + c * 16 + m] = __float2half(acc[c][r] * dw[r]);
        }
    }
}

// ---------------- GEMM2: x1h[M,128]fp16 @ W2t[16,128]fp16 -> fp16, *= dis[row] ----------------
__global__ __launch_bounds__(256) void gemm2_mfma(
        const __half* __restrict__ A, const __half* __restrict__ W2t,
        const float* __restrict__ dis, __half* __restrict__ C, int M) {
    int wave = threadIdx.x >> 6;
    int lane = threadIdx.x & 63;
    int m = lane & 15, q = lane >> 4;
    int row0 = (blockIdx.x * 4 + wave) * 16;
    int arow = row0 + m;
    bool aval = arow < M;
    const __half* ar = A + (size_t)arow * 128 + q * 8;
    f32x4 acc = (f32x4){0.f, 0.f, 0.f, 0.f};
    #pragma unroll
    for (int k0 = 0; k0 < 128; k0 += 32) {
        f16x8 a;
        if (aval) {
            a = *(const f16x8*)(ar + k0);
        } else {
            #pragma unroll
            for (int i = 0; i < 8; ++i) a[i] = (_Float16)0.f;
        }
        f16x8 b = *(const f16x8*)(W2t + (size_t)m * 128 + k0 + q * 8);
        acc = __builtin_amdgcn_mfma_f32_16x16x32_f16(a, b, acc, 0, 0, 0);
    }
    #pragma unroll
    for (int r = 0; r < 4; ++r) {
        int rr = row0 + q * 4 + r;
        if (rr < M)
            C[(size_t)rr * 16 + m] = __float2half(acc[r] * dis[rr]);
    }
}

// ---------------- prop128: wave/node, 4 edge slots x 16 lanes x float4, 32 in flight ----------------
__global__ __launch_bounds__(256) void prop128(
        const __half* __restrict__ h, const int* __restrict__ rowptr,
        const int* __restrict__ col, const float* __restrict__ dis,
        const float* __restrict__ bias, __half* __restrict__ out, int N) {
    int n = (blockIdx.x * 256 + threadIdx.x) >> 6;
    if (n >= N) return;
    int lane = threadIdx.x & 63;
    int eo = lane >> 4;
    int q = lane & 15;
    const float4* __restrict__ h4 = (const float4*)h;
    int beg = rowptr[n], end = rowptr[n + 1];
    __half2 acc[4];
    acc[0] = acc[1] = acc[2] = acc[3] = __float2half2_rn(0.f);
    int j = beg + eo;
    for (; j + 28 < end; j += 32) {     // 32 edges in flight per wave
        int s0 = col[j],      s1 = col[j + 4],  s2 = col[j + 8],  s3 = col[j + 12];
        int s4 = col[j + 16], s5 = col[j + 20], s6 = col[j + 24], s7 = col[j + 28];
        H8 u0, u1, u2, u3, u4, u5, u6, u7;
        u0.f = h4[(size_t)s0 * 16 + q];
        u1.f = h4[(size_t)s1 * 16 + q];
        u2.f = h4[(size_t)s2 * 16 + q];
        u3.f = h4[(size_t)s3 * 16 + q];
        u4.f = h4[(size_t)s4 * 16 + q];
        u5.f = h4[(size_t)s5 * 16 + q];
        u6.f = h4[(size_t)s6 * 16 + q];
        u7.f = h4[(size_t)s7 * 16 + q];
        #pragma unroll
        for (int i = 0; i < 4; ++i) acc[i] = __hadd2(acc[i], u0.h[i]);
        #pragma unroll
        for (int i = 0; i < 4; ++i) acc[i] = __hadd2(acc[i], u1.h[i]);
        #pragma unroll
        for (int i = 0; i < 4; ++i) acc[i] = __hadd2(acc[i], u2.h[i]);
        #pragma unroll
        for (int i = 0; i < 4; ++i) acc[i] = __hadd2(acc[i], u3.h[i]);
        #pragma unroll
        for (int i = 0; i < 4; ++i) acc[i] = __hadd2(acc[i], u4.h[i]);
        #pragma unroll
        for (int i = 0; i < 4; ++i) acc[i] = __hadd2(acc[i], u5.h[i]);
        #pragma unroll
        for (int i = 0; i < 4; ++i) acc[i] = __hadd2(acc[i], u6.h[i]);
        #pragma unroll
        for (int i = 0; i < 4; ++i) acc[i] = __hadd2(acc[i], u7.h[i]);
    }
    for (; j + 12 < end; j += 16) {
        int s0 = col[j], s1 = col[j + 4], s2 = col[j + 8], s3 = col[j + 12];
        H8 u0, u1, u2, u3;
        u0.f = h4[(size_t)s0 * 16 + q];
        u1.f = h4[(size_t)s1 * 16 + q];
        u2.f = h4[(size_t)s2 * 16 + q];
        u3.f = h4[(size_t)s3 * 16 + q];
        #pragma unroll
        for (int i = 0; i < 4; ++i) acc[i] = __hadd2(acc[i], u0.h[i]);
        #pragma unroll
        for (int i = 0; i < 4; ++i) acc[i] = __hadd2(acc[i], u1.h[i]);
        #pragma unroll
        for (int i = 0; i < 4; ++i) acc[i] = __hadd2(acc[i], u2.h[i]);
        #pragma unroll
        for (int i = 0; i < 4; ++i) acc[i] = __hadd2(acc[i], u3.h[i]);
    }
    for (; j + 4 < end; j += 8) {
        int s0 = col[j], s1 = col[j + 4];
        H8 u0, u1;
        u0.f = h4[(size_t)s0 * 16 + q];
        u1.f = h4[(size_t)s1 * 16 + q];
        #pragma unroll
        for (int i = 0; i < 4; ++i) acc[i] = __hadd2(acc[i], u0.h[i]);
        #pragma unroll
        for (int i = 0; i < 4; ++i) acc[i] = __hadd2(acc[i], u1.h[i]);
    }
    for (; j < end; j += 4) {
        int s = col[j];
        H8 u; u.f = h4[(size_t)s * 16 + q];
        #pragma unroll
        for (int i = 0; i < 4; ++i) acc[i] = __hadd2(acc[i], u.h[i]);
    }
    #pragma unroll
    for (int i = 0; i < 4; ++i) {
        acc[i] = __hadd2(acc[i], shfl_xor_h2(acc[i], 16));
        acc[i] = __hadd2(acc[i], shfl_xor_h2(acc[i], 32));
    }
    if (eo == 0) {
        float dn = dis[n];
        const float4* b4 = (const float4*)bias;
        float4 bA = b4[q * 2];
        float4 bB = b4[q * 2 + 1];
        float2 f0 = __half22float2(acc[0]);
        float2 f1 = __half22float2(acc[1]);
        float2 f2 = __half22float2(acc[2]);
        float2 f3 = __half22float2(acc[3]);
        float o0 = fmaf(dn, f0.x, bA.x), o1 = fmaf(dn, f0.y, bA.y);
        float o2 = fmaf(dn, f1.x, bA.z), o3 = fmaf(dn, f1.y, bA.w);
        float o4 = fmaf(dn, f2.x, bB.x), o5 = fmaf(dn, f2.y, bB.y);
        float o6 = fmaf(dn, f3.x, bB.z), o7 = fmaf(dn, f3.y, bB.w);
        o0 = o0 > 0.f ? o0 : LEAKY * o0;  o1 = o1 > 0.f ? o1 : LEAKY * o1;
        o2 = o2 > 0.f ? o2 : LEAKY * o2;  o3 = o3 > 0.f ? o3 : LEAKY * o3;
        o4 = o4 > 0.f ? o4 : LEAKY * o4;  o5 = o5 > 0.f ? o5 : LEAKY * o5;
        o6 = o6 > 0.f ? o6 : LEAKY * o6;  o7 = o7 > 0.f ? o7 : LEAKY * o7;
        H8 w;
        w.h[0] = __floats2half2_rn(o0, o1);
        w.h[1] = __floats2half2_rn(o2, o3);
        w.h[2] = __floats2half2_rn(o4, o5);
        w.h[3] = __floats2half2_rn(o6, o7);
        ((float4*)out)[(size_t)n * 16 + q] = w.f;
    }
}

// ---------------- prop16: 16 lanes/node, 2 slots x 8 lanes, 16 edges in flight ----------------
// h rows fp16 pre-scaled by dis[src]; output x2 = dis*leaky(dis*sum + b) (pre-scaled fp16)
__global__ __launch_bounds__(256) void prop16(
        const __half* __restrict__ h, const int* __restrict__ rowptr,
        const int* __restrict__ col, const float* __restrict__ dis,
        const float* __restrict__ bias, __half* __restrict__ outp, int N) {
    int t = blockIdx.x * 256 + threadIdx.x;
    int n = t >> 4;
    if (n >= N) return;
    int li = threadIdx.x & 15;
    int eo = li >> 3;
    int hq = li & 7;
    const int* __restrict__ h2i = (const int*)h;
    int beg = rowptr[n], end = rowptr[n + 1];
    __half2 acc = __float2half2_rn(0.f);
    int j = beg + eo;
    for (; j + 14 < end; j += 16) {     // 16 edges in flight per node
        H2 u0, u1, u2, u3, u4, u5, u6, u7;
        u0.i = h2i[(size_t)col[j]      * 8 + hq];
        u1.i = h2i[(size_t)col[j + 2]  * 8 + hq];
        u2.i = h2i[(size_t)col[j + 4]  * 8 + hq];
        u3.i = h2i[(size_t)col[j + 6]  * 8 + hq];
        u4.i = h2i[(size_t)col[j + 8]  * 8 + hq];
        u5.i = h2i[(size_t)col[j + 10] * 8 + hq];
        u6.i = h2i[(size_t)col[j + 12] * 8 + hq];
        u7.i = h2i[(size_t)col[j + 14] * 8 + hq];
        acc = __hadd2(acc, u0.h); acc = __hadd2(acc, u1.h);
        acc = __hadd2(acc, u2.h); acc = __hadd2(acc, u3.h);
        acc = __hadd2(acc, u4.h); acc = __hadd2(acc, u5.h);
        acc = __hadd2(acc, u6.h); acc = __hadd2(acc, u7.h);
    }
    for (; j + 6 < end; j += 8) {
        H2 u0, u1, u2, u3;
        u0.i = h2i[(size_t)col[j]     * 8 + hq];
        u1.i = h2i[(size_t)col[j + 2] * 8 + hq];
        u2.i = h2i[(size_t)col[j + 4] * 8 + hq];
        u3.i = h2i[(size_t)col[j + 6] * 8 + hq];
        acc = __hadd2(acc, u0.h); acc = __hadd2(acc, u1.h);
        acc = __hadd2(acc, u2.h); acc = __hadd2(acc, u3.h);
    }
    for (; j < end; j += 2) {
        H2 u; u.i = h2i[(size_t)col[j] * 8 + hq];
        acc = __hadd2(acc, u.h);
    }
    acc = __hadd2(acc, shfl_xor_h2(acc, 8));
    if (eo == 0) {
        float dn = dis[n];
        float2 f = __half22float2(acc);
        float ox = fmaf(dn, f.x, bias[hq * 2]);
        float oy = fmaf(dn, f.y, bias[hq * 2 + 1]);
        ox = ox > 0.f ? ox : LEAKY * ox;
        oy = oy > 0.f ? oy : LEAKY * oy;
        ox *= dn; oy *= dn;
        H2 w; w.h = __floats2half2_rn(ox, oy);
        ((int*)outp)[(size_t)n * 8 + hq] = w.i;
    }
}

// ---------------- prop16_gemm3: gather x2 -> p3 (registers) -> @W3 + b3 -> out ----------------
__global__ __launch_bounds__(256) void prop16_gemm3(
        const __half* __restrict__ h, const int* __restrict__ rowptr,
        const int* __restrict__ col, const float* __restrict__ dis,
        const float* __restrict__ W3, const float* __restrict__ b3,
        float* __restrict__ out, int N) {
    __shared__ float sw[640];
    __shared__ float sb[40];
    int t0 = threadIdx.x;
    for (int i = t0; i < 640; i += 256) sw[i] = W3[i];
    if (t0 < 40) sb[t0] = b3[t0];
    __syncthreads();
    int t = blockIdx.x * 256 + t0;
    int n = t >> 4;
    if (n >= N) return;
    int li = t0 & 15;
    int eo = li >> 3;
    int hq = li & 7;
    const int* __restrict__ h2i = (const int*)h;
    int beg = rowptr[n], end = rowptr[n + 1];
    __half2 acc = __float2half2_rn(0.f);
    int j = beg + eo;
    for (; j + 14 < end; j += 16) {
        H2 u0, u1, u2, u3, u4, u5, u6, u7;
        u0.i = h2i[(size_t)col[j]      * 8 + hq];
        u1.i = h2i[(size_t)col[j + 2]  * 8 + hq];
        u2.i = h2i[(size_t)col[j + 4]  * 8 + hq];
        u3.i = h2i[(size_t)col[j + 6]  * 8 + hq];
        u4.i = h2i[(size_t)col[j + 8]  * 8 + hq];
        u5.i = h2i[(size_t)col[j + 10] * 8 + hq];
        u6.i = h2i[(size_t)col[j + 12] * 8 + hq];
        u7.i = h2i[(size_t)col[j + 14] * 8 + hq];
        acc = __hadd2(acc, u0.h); acc = __hadd2(acc, u1.h);
        acc = __hadd2(acc, u2.h); acc = __hadd2(acc, u3.h);
        acc = __hadd2(acc, u4.h); acc = __hadd2(acc, u5.h);
        acc = __hadd2(acc, u6.h); acc = __hadd2(acc, u7.h);
    }
    for (; j + 6 < end; j += 8) {
        H2 u0, u1, u2, u3;
        u0.i = h2i[(size_t)col[j]     * 8 + hq];
        u1.i = h2i[(size_t)col[j + 2] * 8 + hq];
        u2.i = h2i[(size_t)col[j + 4] * 8 + hq];
        u3.i = h2i[(size_t)col[j + 6] * 8 + hq];
        acc = __hadd2(acc, u0.h); acc = __hadd2(acc, u1.h);
        acc = __hadd2(acc, u2.h); acc = __hadd2(acc, u3.h);
    }
    for (; j < end; j += 2) {
        H2 u; u.i = h2i[(size_t)col[j] * 8 + hq];
        acc = __hadd2(acc, u.h);
    }
    acc = __hadd2(acc, shfl_xor_h2(acc, 8));
    // every lane now holds full p3 fragment for its hq (both eo copies identical)
    float dn = dis[n];
    int slot = (t0 & 63) & ~15;          // wave-lane base of this 16-lane slot
    H2 av; av.h = acc;
    float oA = 0.f, oB = 0.f, oC = 0.f;  // cols li, li+16, li+32
    #pragma unroll
    for (int hh = 0; hh < 8; ++hh) {
        H2 u; u.i = __shfl(av.i, slot + hh);
        float2 p = __half22float2(u.h);
        float p0 = dn * p.x, p1 = dn * p.y;
        int k0 = hh * 2;
        oA = fmaf(p0, sw[k0 * 40 + li],            oA);
        oA = fmaf(p1, sw[(k0 + 1) * 40 + li],      oA);
        oB = fmaf(p0, sw[k0 * 40 + li + 16],       oB);
        oB = fmaf(p1, sw[(k0 + 1) * 40 + li + 16], oB);
        if (li < 8) {
            oC = fmaf(p0, sw[k0 * 40 + li + 32],       oC);
            oC = fmaf(p1, sw[(k0 + 1) * 40 + li + 32], oC);
        }
    }
    float* orow = out + (size_t)n * 40;
    orow[li]      = oA + sb[li];
    orow[li + 16] = oB + sb[li + 16];
    if (li < 8) orow[li + 32] = oC + sb[li + 32];
}

// ---------------- launch ----------------

extern "C" void kernel_launch(void* const* d_in, const int* in_sizes, int n_in,
                              void* d_out, int out_size, void* d_ws, size_t ws_size,
                              hipStream_t stream) {
    const float* x  = (const float*)d_in[0];
    const int*   ei = (const int*)d_in[1];
    const float* W1 = (const float*)d_in[2];
    const float* b1 = (const float*)d_in[3];
    const float* W2 = (const float*)d_in[4];
    const float* b2 = (const float*)d_in[5];
    const float* W3 = (const float*)d_in[6];
    const float* b3 = (const float*)d_in[7];
    float* out = (float*)d_out;

    int N = in_sizes[0] / 256;   // 100000
    int E = in_sizes[1] / 2;     // 3200000
    const int* src = ei;
    const int* dst = ei + E;
    int NBUK = (N + BSZ - 1) >> BP;   // 1563

    char* w = (char*)d_ws;
    auto alloc = [&](size_t bytes) {
        char* p = w;
        w += (bytes + 255) & ~(size_t)255;
        return p;
    };
    int*    rowptr  = (int*)   alloc((size_t)(N + 1) * 4);
    int*    bhist   = (int*)   alloc((size_t)NBUK * 4);
    int*    bbase   = (int*)   alloc((size_t)(NBUK + 1) * 4);
    int*    bcur    = (int*)   alloc((size_t)NBUK * 4);
    int*    ebuf    = (int*)   alloc((size_t)E * 4);
    int*    colx    = (int*)   alloc((size_t)(E + N) * 4);
    float*  dis     = (float*) alloc((size_t)N * 4);
    __half* W1t     = (__half*)alloc((size_t)128 * 256 * 2);
    __half* W2t     = (__half*)alloc((size_t)16 * 128 * 2);
    __half* h1h     = (__half*)alloc((size_t)N * 128 * 2);
    __half* x1h     = (__half*)alloc((size_t)N * 128 * 2);
    __half* h2h     = (__half*)alloc((size_t)N * 16 * 2);
    __half* x2h     = (__half*)alloc((size_t)N * 16 * 2);

    (void)hipMemsetAsync(bhist, 0, (size_t)NBUK * 4, stream);
    kinit   <<<392, 256, 0, stream>>>(dst, bhist, E, NBUK, W1, W2, W1t, W2t);
    bscan   <<<1, 1024, 0, stream>>>(bhist, bbase, bcur, NBUK);
    int SC_BLOCKS = 256;
    int chunk = (E + SC_BLOCKS - 1) / SC_BLOCKS;
    kscatter2<<<SC_BLOCKS, 256, 0, stream>>>(src, dst, bcur, ebuf, E, NBUK, chunk);
    kcount_scan<<<NBUK, 256, 0, stream>>>(ebuf, bbase, rowptr, dis, N);
    kplace  <<<NBUK, 256, 0, stream>>>(ebuf, bbase, rowptr, colx, N);

    int gtiles = (N + 63) / 64;
    gemm1_mfma<<<gtiles, 256, 0, stream>>>(x, W1t, dis, h1h, N);
    prop128   <<<(N * 64 + 255) / 256, 256, 0, stream>>>(h1h, rowptr, colx,
                                                         dis, b1, x1h, N);
    gemm2_mfma<<<gtiles, 256, 0, stream>>>(x1h, W2t, dis, h2h, N);
    prop16    <<<(N * 16 + 255) / 256, 256, 0, stream>>>(h2h, rowptr, colx,
                                                         dis, b2, x2h, N);
    prop16_gemm3<<<(N * 16 + 255) / 256, 256, 0, stream>>>(x2h, rowptr, colx,
                                                           dis, W3, b3, out, N);
}